// Round 1
// baseline (222.208 us; speedup 1.0000x reference)
//
#include <hip/hip_runtime.h>
#include <math.h>

#define KC 33          // clusters
#define ED 32          // embedding dim
#define KE (KC * ED)   // 1056
#define BPB 128        // blocks per batch for the two big passes

// ws layout (floats): sums[B*KE] | counts[B*KC] | hinge[B*KC] | centers[B*KE]

__global__ void k_zero(float* __restrict__ ws, int n, float* __restrict__ out) {
    int i = blockIdx.x * blockDim.x + threadIdx.x;
    if (i < n) ws[i] = 0.f;
    if (i == 0) out[0] = 0.f;
}

// Pass 1: per-(b,k) embedding sums + counts.
// Half-wave per point: lane e = dim. LDS atomic adds: lane e -> bank e, only
// 2-way aliasing between wave halves (free per m136).
__global__ __launch_bounds__(256) void k_accum(const float* __restrict__ emb,
                                               const int* __restrict__ lab,
                                               float* __restrict__ sums,
                                               float* __restrict__ counts,
                                               int N) {
    __shared__ float s_sum[KE];
    __shared__ float s_cnt[KC];
    int t = threadIdx.x;
    for (int i = t; i < KE; i += 256) s_sum[i] = 0.f;
    if (t < KC) s_cnt[t] = 0.f;
    __syncthreads();

    int b    = blockIdx.x / BPB;
    int blk  = blockIdx.x % BPB;
    int chunk = N / BPB;              // 512 (multiple of 8)
    int e    = t & 31;
    int slot = t >> 5;                // 8 half-waves per 256-thread block
    int base = blk * chunk;

    for (int it = 0; it < chunk; it += 8) {
        int idx = base + it + slot;
        if (idx < N) {
            int p = b * N + idx;
            int k = lab[p];                         // broadcast load per half-wave
            float x = emb[(size_t)p * ED + e];      // 128B coalesced per half-wave
            atomicAdd(&s_sum[k * ED + e], x);
            if (e == 0) atomicAdd(&s_cnt[k], 1.0f);
        }
    }
    __syncthreads();
    for (int i = t; i < KE; i += 256) atomicAdd(&sums[(size_t)b * KE + i], s_sum[i]);
    if (t < KC) atomicAdd(&counts[b * KC + t], s_cnt[t]);
}

__global__ __launch_bounds__(256) void k_centers(const float* __restrict__ sums,
                                                 const float* __restrict__ counts,
                                                 float* __restrict__ ctr, int total) {
    int i = blockIdx.x * blockDim.x + threadIdx.x;
    if (i < total) {
        int bk = i / ED;   // = b*KC + k   (since KE = KC*ED)
        ctr[i] = sums[i] / fmaxf(counts[bk], 1.0f);
    }
}

// Pass 2: per-point hinge = max(||x - c_label|| - 0.5, 0), segment-summed per (b,k).
__global__ __launch_bounds__(256) void k_hinge(const float* __restrict__ emb,
                                               const int* __restrict__ lab,
                                               const float* __restrict__ ctr,
                                               float* __restrict__ hinge,
                                               int N) {
    __shared__ float s_ctr[KE];
    __shared__ float s_hng[KC];
    int t   = threadIdx.x;
    int b   = blockIdx.x / BPB;
    int blk = blockIdx.x % BPB;
    for (int i = t; i < KE; i += 256) s_ctr[i] = ctr[(size_t)b * KE + i];
    if (t < KC) s_hng[t] = 0.f;
    __syncthreads();

    int chunk = N / BPB;
    int e    = t & 31;
    int slot = t >> 5;
    int base = blk * chunk;

    for (int it = 0; it < chunk; it += 8) {
        int idx = base + it + slot;
        if (idx < N) {
            int p = b * N + idx;
            int k = lab[p];
            float x = emb[(size_t)p * ED + e];
            float d = x - s_ctr[k * ED + e];
            float d2 = d * d;
            // reduce across the 32-lane half-wave (masks < 32 never cross halves)
            d2 += __shfl_xor(d2, 1);
            d2 += __shfl_xor(d2, 2);
            d2 += __shfl_xor(d2, 4);
            d2 += __shfl_xor(d2, 8);
            d2 += __shfl_xor(d2, 16);
            if (e == 0 && k > 0) {
                float dist = sqrtf(fmaxf(d2, 1e-12f));
                float h = dist - 0.5f;
                if (h > 0.f) atomicAdd(&s_hng[k], h);
            }
        }
    }
    __syncthreads();
    if (t < KC) atomicAdd(&hinge[b * KC + t], s_hng[t]);
}

// Epilogue: one block per batch. variance / pairwise-distance / reg terms.
__global__ __launch_bounds__(256) void k_final(const float* __restrict__ counts,
                                               const float* __restrict__ hinge,
                                               const float* __restrict__ ctr,
                                               float* __restrict__ out, int B) {
    __shared__ float s_ctr[KE];
    __shared__ float s_var[KC];
    __shared__ float s_reg[KC];
    __shared__ int   s_prs[KC];
    __shared__ float s_red[256];
    int b = blockIdx.x;
    int t = threadIdx.x;

    for (int i = t; i < KE; i += 256) s_ctr[i] = ctr[(size_t)b * KE + i];
    if (t < KC) {
        float cnt = counts[b * KC + t];
        int present = (t > 0 && cnt > 0.f) ? 1 : 0;
        s_prs[t] = present;
        s_var[t] = present ? hinge[b * KC + t] / fmaxf(cnt, 1.f) : 0.f;
    }
    __syncthreads();
    if (t < KC) {
        float n2 = 0.f;
        for (int e2 = 0; e2 < ED; e2++) { float c = s_ctr[t * ED + e2]; n2 += c * c; }
        s_reg[t] = s_prs[t] ? sqrtf(fmaxf(n2, 1e-12f)) : 0.f;
    }
    __syncthreads();

    // pairwise hinge over upper triangle
    float psum = 0.f;
    for (int q = t; q < KC * KC; q += 256) {
        int i = q / KC, j = q % KC;
        if (i < j && s_prs[i] && s_prs[j]) {
            float d2 = 0.f;
            for (int e2 = 0; e2 < ED; e2++) {
                float d = s_ctr[i * ED + e2] - s_ctr[j * ED + e2];
                d2 += d * d;
            }
            float cd = sqrtf(fmaxf(d2, 1e-12f));
            psum += fmaxf(3.0f - cd, 0.f);   // 2*DELTA_D = 3.0
        }
    }
    s_red[t] = psum;
    __syncthreads();
    for (int s = 128; s > 0; s >>= 1) {
        if (t < s) s_red[t] += s_red[t + s];
        __syncthreads();
    }

    if (t == 0) {
        float var = 0.f, reg = 0.f; int n = 0;
        for (int k = 0; k < KC; k++) { var += s_var[k]; reg += s_reg[k]; n += s_prs[k]; }
        float nf = (float)n;
        float variance_term = var / fmaxf(nf, 1.f);
        float npairs = nf * (nf - 1.f) * 0.5f;
        float distance_term = s_red[0] / fmaxf(npairs, 1.f);
        float reg_term = reg / fmaxf(nf, 1.f);
        float pb = variance_term + distance_term + 0.001f * reg_term;  // ALPHA=BETA=1, GAMMA=0.001
        if (n == 0) pb = 0.f;
        atomicAdd(out, pb / (float)B);
    }
}

extern "C" void kernel_launch(void* const* d_in, const int* in_sizes, int n_in,
                              void* d_out, int out_size, void* d_ws, size_t ws_size,
                              hipStream_t stream) {
    const float* emb = (const float*)d_in[0];
    const int*   lab = (const int*)d_in[1];
    float* out = (float*)d_out;

    const int B = 8;
    const int N = in_sizes[1] / B;   // 65536

    float* sums   = (float*)d_ws;
    float* counts = sums + (size_t)B * KE;
    float* hng    = counts + (size_t)B * KC;
    float* ctr    = hng + (size_t)B * KC;

    int zn = B * KE + 2 * B * KC;    // sums + counts + hinge
    k_zero<<<(zn + 255) / 256, 256, 0, stream>>>(sums, zn, out);
    k_accum<<<B * BPB, 256, 0, stream>>>(emb, lab, sums, counts, N);
    k_centers<<<(B * KE + 255) / 256, 256, 0, stream>>>(sums, counts, ctr, B * KE);
    k_hinge<<<B * BPB, 256, 0, stream>>>(emb, lab, ctr, hng, N);
    k_final<<<B, 256, 0, stream>>>(counts, hng, ctr, out, B);
}

// Round 2
// 209.002 us; speedup vs baseline: 1.0632x; 1.0632x over previous
//
#include <hip/hip_runtime.h>
#include <math.h>

#define KC 33          // clusters
#define ED 32          // embedding dim
#define KE (KC * ED)   // 1056
#define BPB 128        // blocks per batch for the two big passes
#define UNR 8          // manual unroll: 8 iterations of loads in flight

// ws layout (floats): sums[B*KE] | counts[B*KC] | hinge[B*KC] | centers[B*KE]

__global__ void k_zero(float* __restrict__ ws, int n, float* __restrict__ out) {
    int i = blockIdx.x * blockDim.x + threadIdx.x;
    if (i < n) ws[i] = 0.f;
    if (i == 0) out[0] = 0.f;
}

// Pass 1: per-(b,k) embedding sums + counts.
// Half-wave per point: lane e = dim -> LDS bank e; only 2-way aliasing between
// wave halves (free, m136). Batched loads (UNR deep) for memory-level
// parallelism: ~2KB in flight per wave instead of 256B.
__global__ __launch_bounds__(256) void k_accum(const float* __restrict__ emb,
                                               const int* __restrict__ lab,
                                               float* __restrict__ sums,
                                               float* __restrict__ counts,
                                               int N) {
    __shared__ float s_sum[KE];
    __shared__ float s_cnt[KC];
    int t = threadIdx.x;
    for (int i = t; i < KE; i += 256) s_sum[i] = 0.f;
    if (t < KC) s_cnt[t] = 0.f;
    __syncthreads();

    int b     = blockIdx.x / BPB;
    int blk   = blockIdx.x % BPB;
    int chunk = N / BPB;              // 512 for N=65536
    int e     = t & 31;
    int slot  = t >> 5;               // 8 half-waves per 256-thread block
    int base  = blk * chunk;

    int it = 0;
    int main_end = (chunk / (8 * UNR)) * (8 * UNR);
    for (; it < main_end; it += 8 * UNR) {
        float x[UNR];
        int   kk[UNR];
#pragma unroll
        for (int u = 0; u < UNR; u++) {
            int idx = base + it + u * 8 + slot;
            int p = b * N + idx;
            kk[u] = lab[p];                          // broadcast per half-wave
            x[u]  = emb[(size_t)p * ED + e];         // 128B coalesced per half-wave
        }
#pragma unroll
        for (int u = 0; u < UNR; u++) {
            atomicAdd(&s_sum[kk[u] * ED + e], x[u]);
        }
#pragma unroll
        for (int u = 0; u < UNR; u++) {
            if (e == 0) atomicAdd(&s_cnt[kk[u]], 1.0f);
        }
    }
    // tail (not taken for N=65536, BPB=128)
    for (; it < chunk; it += 8) {
        int idx = base + it + slot;
        if (idx < N) {
            int p = b * N + idx;
            int k = lab[p];
            float x = emb[(size_t)p * ED + e];
            atomicAdd(&s_sum[k * ED + e], x);
            if (e == 0) atomicAdd(&s_cnt[k], 1.0f);
        }
    }
    __syncthreads();
    for (int i = t; i < KE; i += 256) atomicAdd(&sums[(size_t)b * KE + i], s_sum[i]);
    if (t < KC) atomicAdd(&counts[b * KC + t], s_cnt[t]);
}

__global__ __launch_bounds__(256) void k_centers(const float* __restrict__ sums,
                                                 const float* __restrict__ counts,
                                                 float* __restrict__ ctr, int total) {
    int i = blockIdx.x * blockDim.x + threadIdx.x;
    if (i < total) {
        int bk = i / ED;   // = b*KC + k   (since KE = KC*ED)
        ctr[i] = sums[i] / fmaxf(counts[bk], 1.0f);
    }
}

// Pass 2: per-point hinge = max(||x - c_label|| - 0.5, 0), segment-summed per (b,k).
__global__ __launch_bounds__(256) void k_hinge(const float* __restrict__ emb,
                                               const int* __restrict__ lab,
                                               const float* __restrict__ ctr,
                                               float* __restrict__ hinge,
                                               int N) {
    __shared__ float s_ctr[KE];
    __shared__ float s_hng[KC];
    int t   = threadIdx.x;
    int b   = blockIdx.x / BPB;
    int blk = blockIdx.x % BPB;
    for (int i = t; i < KE; i += 256) s_ctr[i] = ctr[(size_t)b * KE + i];
    if (t < KC) s_hng[t] = 0.f;
    __syncthreads();

    int chunk = N / BPB;
    int e     = t & 31;
    int slot  = t >> 5;
    int base  = blk * chunk;

    int it = 0;
    int main_end = (chunk / (8 * UNR)) * (8 * UNR);
    for (; it < main_end; it += 8 * UNR) {
        float x[UNR];
        int   kk[UNR];
#pragma unroll
        for (int u = 0; u < UNR; u++) {
            int idx = base + it + u * 8 + slot;
            int p = b * N + idx;
            kk[u] = lab[p];
            x[u]  = emb[(size_t)p * ED + e];
        }
#pragma unroll
        for (int u = 0; u < UNR; u++) {
            float d = x[u] - s_ctr[kk[u] * ED + e];
            float d2 = d * d;
            d2 += __shfl_xor(d2, 1);
            d2 += __shfl_xor(d2, 2);
            d2 += __shfl_xor(d2, 4);
            d2 += __shfl_xor(d2, 8);
            d2 += __shfl_xor(d2, 16);
            if (e == 0 && kk[u] > 0) {
                float dist = sqrtf(fmaxf(d2, 1e-12f));
                float h = dist - 0.5f;
                if (h > 0.f) atomicAdd(&s_hng[kk[u]], h);
            }
        }
    }
    for (; it < chunk; it += 8) {
        int idx = base + it + slot;
        if (idx < N) {
            int p = b * N + idx;
            int k = lab[p];
            float x = emb[(size_t)p * ED + e];
            float d = x - s_ctr[k * ED + e];
            float d2 = d * d;
            d2 += __shfl_xor(d2, 1);
            d2 += __shfl_xor(d2, 2);
            d2 += __shfl_xor(d2, 4);
            d2 += __shfl_xor(d2, 8);
            d2 += __shfl_xor(d2, 16);
            if (e == 0 && k > 0) {
                float dist = sqrtf(fmaxf(d2, 1e-12f));
                float h = dist - 0.5f;
                if (h > 0.f) atomicAdd(&s_hng[k], h);
            }
        }
    }
    __syncthreads();
    if (t < KC) atomicAdd(&hinge[b * KC + t], s_hng[t]);
}

// Epilogue: one block per batch. variance / pairwise-distance / reg terms.
__global__ __launch_bounds__(256) void k_final(const float* __restrict__ counts,
                                               const float* __restrict__ hinge,
                                               const float* __restrict__ ctr,
                                               float* __restrict__ out, int B) {
    __shared__ float s_ctr[KE];
    __shared__ float s_var[KC];
    __shared__ float s_reg[KC];
    __shared__ int   s_prs[KC];
    __shared__ float s_red[256];
    int b = blockIdx.x;
    int t = threadIdx.x;

    for (int i = t; i < KE; i += 256) s_ctr[i] = ctr[(size_t)b * KE + i];
    if (t < KC) {
        float cnt = counts[b * KC + t];
        int present = (t > 0 && cnt > 0.f) ? 1 : 0;
        s_prs[t] = present;
        s_var[t] = present ? hinge[b * KC + t] / fmaxf(cnt, 1.f) : 0.f;
    }
    __syncthreads();
    if (t < KC) {
        float n2 = 0.f;
        for (int e2 = 0; e2 < ED; e2++) { float c = s_ctr[t * ED + e2]; n2 += c * c; }
        s_reg[t] = s_prs[t] ? sqrtf(fmaxf(n2, 1e-12f)) : 0.f;
    }
    __syncthreads();

    // pairwise hinge over upper triangle
    float psum = 0.f;
    for (int q = t; q < KC * KC; q += 256) {
        int i = q / KC, j = q % KC;
        if (i < j && s_prs[i] && s_prs[j]) {
            float d2 = 0.f;
            for (int e2 = 0; e2 < ED; e2++) {
                float d = s_ctr[i * ED + e2] - s_ctr[j * ED + e2];
                d2 += d * d;
            }
            float cd = sqrtf(fmaxf(d2, 1e-12f));
            psum += fmaxf(3.0f - cd, 0.f);   // 2*DELTA_D = 3.0
        }
    }
    s_red[t] = psum;
    __syncthreads();
    for (int s = 128; s > 0; s >>= 1) {
        if (t < s) s_red[t] += s_red[t + s];
        __syncthreads();
    }

    if (t == 0) {
        float var = 0.f, reg = 0.f; int n = 0;
        for (int k = 0; k < KC; k++) { var += s_var[k]; reg += s_reg[k]; n += s_prs[k]; }
        float nf = (float)n;
        float variance_term = var / fmaxf(nf, 1.f);
        float npairs = nf * (nf - 1.f) * 0.5f;
        float distance_term = s_red[0] / fmaxf(npairs, 1.f);
        float reg_term = reg / fmaxf(nf, 1.f);
        float pb = variance_term + distance_term + 0.001f * reg_term;  // ALPHA=BETA=1, GAMMA=0.001
        if (n == 0) pb = 0.f;
        atomicAdd(out, pb / (float)B);
    }
}

extern "C" void kernel_launch(void* const* d_in, const int* in_sizes, int n_in,
                              void* d_out, int out_size, void* d_ws, size_t ws_size,
                              hipStream_t stream) {
    const float* emb = (const float*)d_in[0];
    const int*   lab = (const int*)d_in[1];
    float* out = (float*)d_out;

    const int B = 8;
    const int N = in_sizes[1] / B;   // 65536

    float* sums   = (float*)d_ws;
    float* counts = sums + (size_t)B * KE;
    float* hng    = counts + (size_t)B * KC;
    float* ctr    = hng + (size_t)B * KC;

    int zn = B * KE + 2 * B * KC;    // sums + counts + hinge
    k_zero<<<(zn + 255) / 256, 256, 0, stream>>>(sums, zn, out);
    k_accum<<<B * BPB, 256, 0, stream>>>(emb, lab, sums, counts, N);
    k_centers<<<(B * KE + 255) / 256, 256, 0, stream>>>(sums, counts, ctr, B * KE);
    k_hinge<<<B * BPB, 256, 0, stream>>>(emb, lab, ctr, hng, N);
    k_final<<<B, 256, 0, stream>>>(counts, hng, ctr, out, B);
}

// Round 3
// 153.665 us; speedup vs baseline: 1.4461x; 1.3601x over previous
//
#include <hip/hip_runtime.h>
#include <math.h>

#define KC 33          // clusters
#define ED 32          // embedding dim
#define KE (KC * ED)   // 1056
#define BPB 128        // blocks per batch for the two big passes
#define TP 128         // points per staged tile
#define NSLOT 8        // half-waves per 256-thread block

// ws layout (floats): sums[B*KE] | counts[B*KC] | var[B] | ctr[B*KE] | inv[B*KC]

__global__ void k_zero(float* __restrict__ ws, int n, float* __restrict__ out) {
    int i = blockIdx.x * blockDim.x + threadIdx.x;
    if (i < n) ws[i] = 0.f;
    if (i == 0) out[0] = 0.f;
}

// Pass 1: per-(b,k) sums + counts.
// Phase A: dense float4 staging of a 128-point tile (fully independent loads).
// Phase B: half-wave per point, lane e = dim; NON-ATOMIC RMW into per-half-wave
// private copies s_priv[slot][k][e] (bank = e, race-free: slot is private).
__global__ __launch_bounds__(256) void k_accum(const float* __restrict__ emb,
                                               const int* __restrict__ lab,
                                               float* __restrict__ sums,
                                               float* __restrict__ counts,
                                               int N) {
    __shared__ __align__(16) float s_tile[TP * ED];   // 16 KB
    __shared__ float s_priv[NSLOT * KE];              // 33 KB
    __shared__ float s_cntp[NSLOT * KC];
    __shared__ int   s_lab[TP];
    int t = threadIdx.x;
    for (int i = t; i < NSLOT * KE; i += 256) s_priv[i] = 0.f;
    for (int i = t; i < NSLOT * KC; i += 256) s_cntp[i] = 0.f;

    int b     = blockIdx.x / BPB;
    int blk   = blockIdx.x % BPB;
    int chunk = N / BPB;              // 512
    int e     = t & 31;
    int slot  = t >> 5;
    size_t pbase = (size_t)b * N + (size_t)blk * chunk;
    __syncthreads();

    for (int tb = 0; tb < chunk / TP; tb++) {
        size_t tstart = pbase + (size_t)tb * TP;
        const float4* g4 = (const float4*)(emb + tstart * ED);
        float4* s4 = (float4*)s_tile;
#pragma unroll
        for (int r = 0; r < (TP * ED / 4) / 256; r++)   // 4 independent float4 loads
            s4[t + r * 256] = g4[t + r * 256];
        if (t < TP) s_lab[t] = lab[tstart + t];
        __syncthreads();

#pragma unroll 4
        for (int step = 0; step < TP / NSLOT; step++) {
            int pt = step * NSLOT + slot;
            float x = s_tile[pt * ED + e];
            int k = s_lab[pt];
            s_priv[slot * KE + k * ED + e] += x;        // private: no atomic
            if (e == 0) s_cntp[slot * KC + k] += 1.f;   // private: no atomic
        }
        __syncthreads();
    }

    // flush private copies -> global (one atomic per element per block)
    for (int i = t; i < KE; i += 256) {
        float v = 0.f;
#pragma unroll
        for (int s = 0; s < NSLOT; s++) v += s_priv[s * KE + i];
        atomicAdd(&sums[(size_t)b * KE + i], v);
    }
    if (t < KC) {
        float v = 0.f;
#pragma unroll
        for (int s = 0; s < NSLOT; s++) v += s_cntp[s * KC + t];
        atomicAdd(&counts[b * KC + t], v);
    }
}

// centers + per-cluster 1/count (0 for k==0, so pass 2 needs no per-cluster scatter)
__global__ void k_centers(const float* __restrict__ sums,
                          const float* __restrict__ counts,
                          float* __restrict__ ctr, float* __restrict__ inv, int B) {
    int i = blockIdx.x * blockDim.x + threadIdx.x;
    int tot1 = B * KE;
    if (i < tot1) {
        ctr[i] = sums[i] / fmaxf(counts[i / ED], 1.0f);
    } else if (i < tot1 + B * KC) {
        int j = i - tot1;
        int k = j % KC;
        inv[j] = (k > 0) ? 1.0f / fmaxf(counts[j], 1.0f) : 0.f;
    }
}

// Pass 2: variance term as a single scalar per batch:
//   var[b] = sum_points max(||x-c_lab||-0.5, 0) * inv[lab]
// No per-cluster scatter, no atomics in the hot loop.
__global__ __launch_bounds__(256) void k_hinge(const float* __restrict__ emb,
                                               const int* __restrict__ lab,
                                               const float* __restrict__ ctr,
                                               const float* __restrict__ inv,
                                               float* __restrict__ var, int N) {
    __shared__ __align__(16) float s_tile[TP * ED];
    __shared__ float s_ctr[KE];
    __shared__ float s_inv[KC];
    __shared__ int   s_lab[TP];
    __shared__ float s_red[4];
    int t    = threadIdx.x;
    int b    = blockIdx.x / BPB;
    int blk  = blockIdx.x % BPB;
    int chunk = N / BPB;
    int e    = t & 31;
    int slot = t >> 5;
    size_t pbase = (size_t)b * N + (size_t)blk * chunk;

    for (int i = t; i < KE; i += 256) s_ctr[i] = ctr[(size_t)b * KE + i];
    if (t < KC) s_inv[t] = inv[b * KC + t];
    float hs = 0.f;

    for (int tb = 0; tb < chunk / TP; tb++) {
        size_t tstart = pbase + (size_t)tb * TP;
        const float4* g4 = (const float4*)(emb + tstart * ED);
        float4* s4 = (float4*)s_tile;
#pragma unroll
        for (int r = 0; r < (TP * ED / 4) / 256; r++)
            s4[t + r * 256] = g4[t + r * 256];
        if (t < TP) s_lab[t] = lab[tstart + t];
        __syncthreads();

#pragma unroll 4
        for (int step = 0; step < TP / NSLOT; step++) {
            int pt = step * NSLOT + slot;
            float x = s_tile[pt * ED + e];
            int k = s_lab[pt];
            float d = x - s_ctr[k * ED + e];
            float d2 = d * d;
            d2 += __shfl_xor(d2, 1);
            d2 += __shfl_xor(d2, 2);
            d2 += __shfl_xor(d2, 4);
            d2 += __shfl_xor(d2, 8);
            d2 += __shfl_xor(d2, 16);
            float dist = sqrtf(fmaxf(d2, 1e-12f));
            hs += fmaxf(dist - 0.5f, 0.f) * s_inv[k];   // all 32 lanes of a half add same h
        }
        __syncthreads();
    }

    // block reduction: every lane holds h-sums replicated 32x within its half-wave
    hs += __shfl_xor(hs, 1);
    hs += __shfl_xor(hs, 2);
    hs += __shfl_xor(hs, 4);
    hs += __shfl_xor(hs, 8);
    hs += __shfl_xor(hs, 16);
    hs += __shfl_xor(hs, 32);
    if ((t & 63) == 0) s_red[t >> 6] = hs;
    __syncthreads();
    if (t == 0) {
        float v = s_red[0] + s_red[1] + s_red[2] + s_red[3];
        atomicAdd(&var[b], v * (1.0f / 32.0f));   // undo 32x lane replication
    }
}

// Epilogue: one block per batch.
__global__ __launch_bounds__(256) void k_final(const float* __restrict__ counts,
                                               const float* __restrict__ var,
                                               const float* __restrict__ ctr,
                                               float* __restrict__ out, int B) {
    __shared__ float s_ctr[KE];
    __shared__ float s_reg[KC];
    __shared__ int   s_prs[KC];
    __shared__ float s_red[256];
    int b = blockIdx.x;
    int t = threadIdx.x;

    for (int i = t; i < KE; i += 256) s_ctr[i] = ctr[(size_t)b * KE + i];
    if (t < KC) {
        float cnt = counts[b * KC + t];
        s_prs[t] = (t > 0 && cnt > 0.f) ? 1 : 0;
    }
    __syncthreads();
    if (t < KC) {
        float n2 = 0.f;
        for (int e2 = 0; e2 < ED; e2++) { float c = s_ctr[t * ED + e2]; n2 += c * c; }
        s_reg[t] = s_prs[t] ? sqrtf(fmaxf(n2, 1e-12f)) : 0.f;
    }
    __syncthreads();

    float psum = 0.f;
    for (int q = t; q < KC * KC; q += 256) {
        int i = q / KC, j = q % KC;
        if (i < j && s_prs[i] && s_prs[j]) {
            float d2 = 0.f;
            for (int e2 = 0; e2 < ED; e2++) {
                float d = s_ctr[i * ED + e2] - s_ctr[j * ED + e2];
                d2 += d * d;
            }
            float cd = sqrtf(fmaxf(d2, 1e-12f));
            psum += fmaxf(3.0f - cd, 0.f);   // 2*DELTA_D = 3.0
        }
    }
    s_red[t] = psum;
    __syncthreads();
    for (int s = 128; s > 0; s >>= 1) {
        if (t < s) s_red[t] += s_red[t + s];
        __syncthreads();
    }

    if (t == 0) {
        float reg = 0.f; int n = 0;
        for (int k = 0; k < KC; k++) { reg += s_reg[k]; n += s_prs[k]; }
        float nf = (float)n;
        float variance_term = var[b] / fmaxf(nf, 1.f);
        float npairs = nf * (nf - 1.f) * 0.5f;
        float distance_term = s_red[0] / fmaxf(npairs, 1.f);
        float reg_term = reg / fmaxf(nf, 1.f);
        float pb = variance_term + distance_term + 0.001f * reg_term;
        if (n == 0) pb = 0.f;
        atomicAdd(out, pb / (float)B);
    }
}

extern "C" void kernel_launch(void* const* d_in, const int* in_sizes, int n_in,
                              void* d_out, int out_size, void* d_ws, size_t ws_size,
                              hipStream_t stream) {
    const float* emb = (const float*)d_in[0];
    const int*   lab = (const int*)d_in[1];
    float* out = (float*)d_out;

    const int B = 8;
    const int N = in_sizes[1] / B;   // 65536

    float* sums   = (float*)d_ws;
    float* counts = sums + (size_t)B * KE;
    float* var    = counts + (size_t)B * KC;
    float* ctr    = var + B;
    float* inv    = ctr + (size_t)B * KE;

    int zn = B * KE + B * KC + B;    // sums + counts + var
    k_zero<<<(zn + 255) / 256, 256, 0, stream>>>(sums, zn, out);
    k_accum<<<B * BPB, 256, 0, stream>>>(emb, lab, sums, counts, N);
    int cn = B * KE + B * KC;
    k_centers<<<(cn + 255) / 256, 256, 0, stream>>>(sums, counts, ctr, inv, B);
    k_hinge<<<B * BPB, 256, 0, stream>>>(emb, lab, ctr, inv, var, N);
    k_final<<<B, 256, 0, stream>>>(counts, var, ctr, out, B);
}

// Round 4
// 134.140 us; speedup vs baseline: 1.6565x; 1.1456x over previous
//
#include <hip/hip_runtime.h>
#include <math.h>

#define KC 33            // clusters
#define ED 32            // embedding dim
#define KE (KC * ED)     // 1056
#define PAD 33           // padded leading dim for LDS tiles

// accum geometry
#define BPB_A 64         // blocks per batch
#define TPA 128          // points per staged tile
#define NSLOT 8          // half-waves per 256-thread block
// hinge geometry
#define BPB_H 128
#define TPH 256          // points per staged tile (1 per thread)

// ws layout (floats): sums[B*KE] | counts[B*KC] | var[B]

__global__ void k_zero(float* __restrict__ ws, int n, float* __restrict__ out) {
    int i = blockIdx.x * blockDim.x + threadIdx.x;
    if (i < n) ws[i] = 0.f;
    if (i == 0) out[0] = 0.f;
}

// Label histogram -> counts. 2MB of labels; 32 blocks per batch, 2048 labels/block.
__global__ __launch_bounds__(256) void k_hist(const int* __restrict__ lab,
                                              float* __restrict__ counts, int N) {
    __shared__ float h[4 * KC];       // per-wave private copies
    int t = threadIdx.x;
    int w = t >> 6;
    if (t < 4 * KC) h[t] = 0.f;
    __syncthreads();
    int b   = blockIdx.x >> 5;
    int blk = blockIdx.x & 31;
    const int4* l4 = (const int4*)(lab + (size_t)b * N + (size_t)blk * 2048);
    int4 a = l4[t];
    int4 c = l4[t + 256];
    float* hw = &h[w * KC];
    atomicAdd(&hw[a.x], 1.f); atomicAdd(&hw[a.y], 1.f);
    atomicAdd(&hw[a.z], 1.f); atomicAdd(&hw[a.w], 1.f);
    atomicAdd(&hw[c.x], 1.f); atomicAdd(&hw[c.y], 1.f);
    atomicAdd(&hw[c.z], 1.f); atomicAdd(&hw[c.w], 1.f);
    __syncthreads();
    if (t < KC)
        atomicAdd(&counts[b * KC + t], h[t] + h[KC + t] + h[2 * KC + t] + h[3 * KC + t]);
}

// Pass 1: per-(b,k) embedding sums. Register-prefetch pipelined staging into a
// +33-padded LDS tile; half-wave per point (lane=dim) non-atomic RMW into
// per-half-wave private copies (bank = e for both halves: 2-way = free).
__global__ __launch_bounds__(256) void k_accum(const float* __restrict__ emb,
                                               const int* __restrict__ lab,
                                               float* __restrict__ sums, int N) {
    __shared__ float s_tile[TPA * PAD];      // 16.9 KB
    __shared__ float s_priv[NSLOT * KE];     // 33 KB
    __shared__ int   s_lab[TPA];
    int t = threadIdx.x;
    for (int i = t; i < NSLOT * KE; i += 256) s_priv[i] = 0.f;

    int b     = blockIdx.x / BPB_A;
    int blk   = blockIdx.x % BPB_A;
    int chunk = N / BPB_A;                   // 1024
    int e     = t & 31;
    int slot  = t >> 5;
    size_t pbase = (size_t)b * N + (size_t)blk * chunk;
    const int NT = chunk / TPA;              // 8 tiles

    // prefetch tile 0
    const float4* g4 = (const float4*)(emb + pbase * ED);
    float4 r0 = g4[t], r1 = g4[t + 256], r2 = g4[t + 512], r3 = g4[t + 768];
    int rl = 0;
    if (t < TPA) rl = lab[pbase + t];
    __syncthreads();                          // priv init done

    for (int tb = 0; tb < NT; tb++) {
        // unpack staged registers into padded tile
        {
            int f, p, m;
            f = t;        p = f >> 3; m = (f & 7) * 4;
            { float* d = &s_tile[PAD * p + m]; d[0]=r0.x; d[1]=r0.y; d[2]=r0.z; d[3]=r0.w; }
            f = t + 256;  p = f >> 3; m = (f & 7) * 4;
            { float* d = &s_tile[PAD * p + m]; d[0]=r1.x; d[1]=r1.y; d[2]=r1.z; d[3]=r1.w; }
            f = t + 512;  p = f >> 3; m = (f & 7) * 4;
            { float* d = &s_tile[PAD * p + m]; d[0]=r2.x; d[1]=r2.y; d[2]=r2.z; d[3]=r2.w; }
            f = t + 768;  p = f >> 3; m = (f & 7) * 4;
            { float* d = &s_tile[PAD * p + m]; d[0]=r3.x; d[1]=r3.y; d[2]=r3.z; d[3]=r3.w; }
        }
        if (t < TPA) s_lab[t] = rl;
        __syncthreads();

        // prefetch next tile while computing this one
        if (tb + 1 < NT) {
            const float4* gn = (const float4*)(emb + (pbase + (size_t)(tb + 1) * TPA) * ED);
            r0 = gn[t]; r1 = gn[t + 256]; r2 = gn[t + 512]; r3 = gn[t + 768];
            if (t < TPA) rl = lab[pbase + (size_t)(tb + 1) * TPA + t];
        }

        float* priv = &s_priv[slot * KE];
#pragma unroll
        for (int st = 0; st < TPA / NSLOT; st++) {
            int pt = st * NSLOT + slot;
            float x = s_tile[pt * PAD + e];
            int   k = s_lab[pt];
            priv[k * ED + e] += x;           // private: no atomic; bank=e: free
        }
        __syncthreads();
    }

    for (int i = t; i < KE; i += 256) {
        float v = 0.f;
#pragma unroll
        for (int s = 0; s < NSLOT; s++) v += s_priv[s * KE + i];
        atomicAdd(&sums[(size_t)b * KE + i], v);
    }
}

// Pass 2: lane-owns-point hinge. Each block recomputes its batch's centers from
// sums/counts (k_centers fused away). var[b] += sum_p max(||x-c||-0.5,0)*inv[k_p].
__global__ __launch_bounds__(256) void k_hinge(const float* __restrict__ emb,
                                               const int* __restrict__ lab,
                                               const float* __restrict__ sums,
                                               const float* __restrict__ counts,
                                               float* __restrict__ var, int N) {
    __shared__ float s_tile[TPH * PAD];      // 33.8 KB
    __shared__ float s_ctr[KC * PAD];        // 4.3 KB, padded
    __shared__ float s_cnt[KC];
    __shared__ float s_inv[KC];
    __shared__ int   s_lab[TPH];
    __shared__ float s_red[4];
    int t     = threadIdx.x;
    int b     = blockIdx.x / BPB_H;
    int blk   = blockIdx.x % BPB_H;
    int chunk = N / BPB_H;                   // 512
    size_t pbase = (size_t)b * N + (size_t)blk * chunk;
    const int NT = chunk / TPH;              // 2 tiles

    // prefetch tile 0 (8 float4 per thread = 1 point per thread)
    const float4* g4 = (const float4*)(emb + pbase * ED);
    float4 r0 = g4[t],        r1 = g4[t + 256],  r2 = g4[t + 512],  r3 = g4[t + 768];
    float4 r4 = g4[t + 1024], r5 = g4[t + 1280], r6 = g4[t + 1536], r7 = g4[t + 1792];
    int rl = lab[pbase + t];

    if (t < KC) {
        float c = counts[b * KC + t];
        s_cnt[t] = fmaxf(c, 1.f);
        s_inv[t] = (t > 0 && c > 0.f) ? 1.f / fmaxf(c, 1.f) : 0.f;
    }
    __syncthreads();
    for (int i = t; i < KE; i += 256) {
        int k = i >> 5, e = i & 31;
        s_ctr[k * PAD + e] = sums[(size_t)b * KE + i] / s_cnt[k];
    }

    float hs = 0.f;
    for (int tb = 0; tb < NT; tb++) {
        {
            int f, p, m;
            f = t;         p = f >> 3; m = (f & 7) * 4;
            { float* d = &s_tile[PAD * p + m]; d[0]=r0.x; d[1]=r0.y; d[2]=r0.z; d[3]=r0.w; }
            f = t + 256;   p = f >> 3; m = (f & 7) * 4;
            { float* d = &s_tile[PAD * p + m]; d[0]=r1.x; d[1]=r1.y; d[2]=r1.z; d[3]=r1.w; }
            f = t + 512;   p = f >> 3; m = (f & 7) * 4;
            { float* d = &s_tile[PAD * p + m]; d[0]=r2.x; d[1]=r2.y; d[2]=r2.z; d[3]=r2.w; }
            f = t + 768;   p = f >> 3; m = (f & 7) * 4;
            { float* d = &s_tile[PAD * p + m]; d[0]=r3.x; d[1]=r3.y; d[2]=r3.z; d[3]=r3.w; }
            f = t + 1024;  p = f >> 3; m = (f & 7) * 4;
            { float* d = &s_tile[PAD * p + m]; d[0]=r4.x; d[1]=r4.y; d[2]=r4.z; d[3]=r4.w; }
            f = t + 1280;  p = f >> 3; m = (f & 7) * 4;
            { float* d = &s_tile[PAD * p + m]; d[0]=r5.x; d[1]=r5.y; d[2]=r5.z; d[3]=r5.w; }
            f = t + 1536;  p = f >> 3; m = (f & 7) * 4;
            { float* d = &s_tile[PAD * p + m]; d[0]=r6.x; d[1]=r6.y; d[2]=r6.z; d[3]=r6.w; }
            f = t + 1792;  p = f >> 3; m = (f & 7) * 4;
            { float* d = &s_tile[PAD * p + m]; d[0]=r7.x; d[1]=r7.y; d[2]=r7.z; d[3]=r7.w; }
        }
        s_lab[t] = rl;
        __syncthreads();

        if (tb + 1 < NT) {
            const float4* gn = (const float4*)(emb + (pbase + (size_t)(tb + 1) * TPH) * ED);
            r0 = gn[t];        r1 = gn[t + 256];  r2 = gn[t + 512];  r3 = gn[t + 768];
            r4 = gn[t + 1024]; r5 = gn[t + 1280]; r6 = gn[t + 1536]; r7 = gn[t + 1792];
            rl = lab[pbase + (size_t)(tb + 1) * TPH + t];
        }

        int   k  = s_lab[t];
        float iv = s_inv[k];
        const float* xr = &s_tile[t * PAD];
        const float* cr = &s_ctr[k * PAD];
        float d2 = 0.f;
#pragma unroll
        for (int j = 0; j < ED; j++) {
            float d = xr[j] - cr[j];
            d2 = fmaf(d, d, d2);
        }
        float dist = sqrtf(fmaxf(d2, 1e-12f));
        hs += fmaxf(dist - 0.5f, 0.f) * iv;
        __syncthreads();
    }

    // block reduction of hs (one value per thread)
    hs += __shfl_xor(hs, 1);  hs += __shfl_xor(hs, 2);  hs += __shfl_xor(hs, 4);
    hs += __shfl_xor(hs, 8);  hs += __shfl_xor(hs, 16); hs += __shfl_xor(hs, 32);
    if ((t & 63) == 0) s_red[t >> 6] = hs;
    __syncthreads();
    if (t == 0)
        atomicAdd(&var[b], s_red[0] + s_red[1] + s_red[2] + s_red[3]);
}

// Epilogue: one block per batch; recompute centers from sums/counts.
__global__ __launch_bounds__(256) void k_final(const float* __restrict__ sums,
                                               const float* __restrict__ counts,
                                               const float* __restrict__ var,
                                               float* __restrict__ out, int B) {
    __shared__ float s_ctr[KE];
    __shared__ float s_cnt[KC];
    __shared__ float s_reg[KC];
    __shared__ int   s_prs[KC];
    __shared__ float s_red[256];
    int b = blockIdx.x;
    int t = threadIdx.x;

    if (t < KC) {
        float c = counts[b * KC + t];
        s_cnt[t] = fmaxf(c, 1.f);
        s_prs[t] = (t > 0 && c > 0.f) ? 1 : 0;
    }
    __syncthreads();
    for (int i = t; i < KE; i += 256)
        s_ctr[i] = sums[(size_t)b * KE + i] / s_cnt[i >> 5];
    __syncthreads();
    if (t < KC) {
        float n2 = 0.f;
        for (int e2 = 0; e2 < ED; e2++) { float c = s_ctr[t * ED + e2]; n2 += c * c; }
        s_reg[t] = s_prs[t] ? sqrtf(fmaxf(n2, 1e-12f)) : 0.f;
    }
    __syncthreads();

    float psum = 0.f;
    for (int q = t; q < KC * KC; q += 256) {
        int i = q / KC, j = q % KC;
        if (i < j && s_prs[i] && s_prs[j]) {
            float d2 = 0.f;
            for (int e2 = 0; e2 < ED; e2++) {
                float d = s_ctr[i * ED + e2] - s_ctr[j * ED + e2];
                d2 += d * d;
            }
            float cd = sqrtf(fmaxf(d2, 1e-12f));
            psum += fmaxf(3.0f - cd, 0.f);   // 2*DELTA_D = 3.0
        }
    }
    s_red[t] = psum;
    __syncthreads();
    for (int s = 128; s > 0; s >>= 1) {
        if (t < s) s_red[t] += s_red[t + s];
        __syncthreads();
    }

    if (t == 0) {
        float reg = 0.f; int n = 0;
        for (int k = 0; k < KC; k++) { reg += s_reg[k]; n += s_prs[k]; }
        float nf = (float)n;
        float variance_term = var[b] / fmaxf(nf, 1.f);
        float npairs = nf * (nf - 1.f) * 0.5f;
        float distance_term = s_red[0] / fmaxf(npairs, 1.f);
        float reg_term = reg / fmaxf(nf, 1.f);
        float pb = variance_term + distance_term + 0.001f * reg_term;
        if (n == 0) pb = 0.f;
        atomicAdd(out, pb / (float)B);
    }
}

extern "C" void kernel_launch(void* const* d_in, const int* in_sizes, int n_in,
                              void* d_out, int out_size, void* d_ws, size_t ws_size,
                              hipStream_t stream) {
    const float* emb = (const float*)d_in[0];
    const int*   lab = (const int*)d_in[1];
    float* out = (float*)d_out;

    const int B = 8;
    const int N = in_sizes[1] / B;   // 65536

    float* sums   = (float*)d_ws;
    float* counts = sums + (size_t)B * KE;
    float* var    = counts + (size_t)B * KC;

    int zn = B * KE + B * KC + B;
    k_zero<<<(zn + 255) / 256, 256, 0, stream>>>(sums, zn, out);
    k_hist<<<B * 32, 256, 0, stream>>>(lab, counts, N);
    k_accum<<<B * BPB_A, 256, 0, stream>>>(emb, lab, sums, N);
    k_hinge<<<B * BPB_H, 256, 0, stream>>>(emb, lab, sums, counts, var, N);
    k_final<<<B, 256, 0, stream>>>(sums, counts, var, out, B);
}